// Round 2
// baseline (683.607 us; speedup 1.0000x reference)
//
#include <hip/hip_runtime.h>

// RNN scan, wave-autonomous version.
//   x <- x + ALPHA*(-x + tanh(x)@J^T + u@b_in^T + c_x + 0.1*n)
// One 64-lane wave per batch element (grid=1024). Lane l owns h=2l,2l+1.
// J rows cached in 200 VGPRs as interleaved float2 pairs -> v_pk_fma_f32.
// r broadcast via per-block LDS, wave-synchronous (no s_barrier -> no
// vmcnt(0) drain, noise prefetch stays in flight).

typedef float v2f __attribute__((ext_vector_type(2)));

#define TSTEPS 750
#define BATCH  1024
#define HID    100

constexpr float ALPHA = 0.1f;   // DT/TAU
constexpr float NSTD  = 0.1f;

__device__ __forceinline__ float ftanh(float x) {
    // tanh(x) = 1 - 2/(exp(2x)+1)
    float e = __expf(2.0f * x);
    return 1.0f - 2.0f * __builtin_amdgcn_rcpf(e + 1.0f);
}

__global__ __launch_bounds__(64, 1) void rnn_scan_kernel(
    const float* __restrict__ input_seq,  // [T,B,4]
    const float* __restrict__ noise,      // [T,B,H]
    const float* __restrict__ J_w,        // [H,H]
    const float* __restrict__ b_in,       // [H,4]
    const float* __restrict__ c_x,        // [H]
    float* __restrict__ states)           // [T,B,H]
{
    const int l = threadIdx.x;            // 0..63
    const int b = blockIdx.x;             // one batch element per wave
    const bool act = (l < HID / 2);       // 50 active lanes
    const int le = act ? l : (HID / 2 - 1);
    const int h0 = 2 * le;

    // Cache J rows h0 and h0+1, interleaved: Jp[k] = {J[h0][k], J[h0+1][k]}.
    // 100 x v2f = 200 VGPRs, all indices compile-time after unroll.
    v2f Jp[HID];
    const float4* rA = reinterpret_cast<const float4*>(J_w + (size_t)h0 * HID);
#pragma unroll
    for (int i = 0; i < 25; ++i) {
        float4 a = rA[i];        // row h0, chunk i
        float4 c = rA[i + 25];   // row h0+1, chunk i
        Jp[4*i+0] = (v2f){a.x, c.x};
        Jp[4*i+1] = (v2f){a.y, c.y};
        Jp[4*i+2] = (v2f){a.z, c.z};
        Jp[4*i+3] = (v2f){a.w, c.w};
    }
    float4 ba = reinterpret_cast<const float4*>(b_in)[h0];
    float4 bc = reinterpret_cast<const float4*>(b_in)[h0 + 1];
    v2f binp0 = (v2f){ba.x, bc.x}, binp1 = (v2f){ba.y, bc.y};
    v2f binp2 = (v2f){ba.z, bc.z}, binp3 = (v2f){ba.w, bc.w};
    v2f cxp = (v2f){c_x[h0], c_x[h0 + 1]};

    __shared__ __align__(16) float rbuf[2][HID];

    v2f x = (v2f){0.f, 0.f};
    if (act) *reinterpret_cast<v2f*>(&rbuf[0][h0]) = (v2f){0.f, 0.f};
    __builtin_amdgcn_wave_barrier();  // sched fence; DS pipe is in-order per wave

    const float* np = noise + (size_t)b * HID + h0;
    const float* up = input_seq + (size_t)b * 4;
    float* sp = states + (size_t)b * HID + h0;

    v2f   nz = *reinterpret_cast<const v2f*>(np);     // t=0
    float4 u = *reinterpret_cast<const float4*>(up);  // wave-uniform -> broadcast

    for (int t = 0; t < TSTEPS; ++t) {
        // Prefetch t+1 inputs; no barrier in the loop so these stay in flight.
        const int tn = (t + 1 < TSTEPS) ? (t + 1) : t;
        v2f   nz_n = *reinterpret_cast<const v2f*>(np + (size_t)tn * BATCH * HID);
        float4 u_n = *reinterpret_cast<const float4*>(up + (size_t)tn * BATCH * 4);

        // Dot products for h0,h0+1 packed. 4 chains: same-chain FMAs 4 instrs
        // apart (8 cyc) > 4-cyc dep latency.
        const float* rb = rbuf[t & 1];
        v2f a0 = {0,0}, a1 = {0,0}, a2 = {0,0}, a3 = {0,0};
#pragma unroll
        for (int i = 0; i < 25; ++i) {
            float4 r4 = *reinterpret_cast<const float4*>(rb + 4 * i);  // uniform -> broadcast
            a0 = __builtin_elementwise_fma(Jp[4*i+0], (v2f){r4.x, r4.x}, a0);
            a1 = __builtin_elementwise_fma(Jp[4*i+1], (v2f){r4.y, r4.y}, a1);
            a2 = __builtin_elementwise_fma(Jp[4*i+2], (v2f){r4.z, r4.z}, a2);
            a3 = __builtin_elementwise_fma(Jp[4*i+3], (v2f){r4.w, r4.w}, a3);
        }
        a0 = __builtin_elementwise_fma(binp0, (v2f){u.x, u.x}, a0);
        a1 = __builtin_elementwise_fma(binp1, (v2f){u.y, u.y}, a1);
        a2 = __builtin_elementwise_fma(binp2, (v2f){u.z, u.z}, a2);
        a3 = __builtin_elementwise_fma(binp3, (v2f){u.w, u.w}, a3);
        v2f s = (a0 + a1) + (a2 + a3);

        v2f pre = s + cxp;
        pre = __builtin_elementwise_fma((v2f){NSTD, NSTD}, nz, pre);
        x = __builtin_elementwise_fma((v2f){ALPHA, ALPHA}, pre - x, x);  // x += a*(pre-x)

        v2f r;
        r.x = ftanh(x.x);
        r.y = ftanh(x.y);

        if (act) {
            *reinterpret_cast<v2f*>(sp + (size_t)t * BATCH * HID) = x;        // states[t]
            *reinterpret_cast<v2f*>(&rbuf[(t + 1) & 1][h0]) = r;              // next r
        }
        __builtin_amdgcn_wave_barrier();  // keep write<->read order; DS in-order per wave
        nz = nz_n;
        u  = u_n;
    }
}

// Readout: out[b,0] = tanh(states[0,b,:]).wout + wb ; out[b,1] = same at T-1.
__global__ __launch_bounds__(64) void rnn_out_kernel(
    const float* __restrict__ states,
    const float* __restrict__ wout_w,
    const float* __restrict__ wout_b,
    float* __restrict__ out)
{
    const int b = blockIdx.x;
    const int l = threadIdx.x;
    const float* s0 = states + (size_t)b * HID;
    const float* sF = states + ((size_t)(TSTEPS - 1) * BATCH + b) * HID;

    float p0 = 0.f, pF = 0.f;
    if (l < HID) {
        p0 = ftanh(s0[l]) * wout_w[l];
        pF = ftanh(sF[l]) * wout_w[l];
    }
    const int l2 = l + 64;
    if (l2 < HID) {
        p0 += ftanh(s0[l2]) * wout_w[l2];
        pF += ftanh(sF[l2]) * wout_w[l2];
    }
#pragma unroll
    for (int off = 32; off > 0; off >>= 1) {
        p0 += __shfl_xor(p0, off, 64);
        pF += __shfl_xor(pF, off, 64);
    }
    if (l == 0) {
        const float wb = wout_b[0];
        out[b * 2 + 0] = p0 + wb;
        out[b * 2 + 1] = pF + wb;
    }
}

extern "C" void kernel_launch(void* const* d_in, const int* in_sizes, int n_in,
                              void* d_out, int out_size, void* d_ws, size_t ws_size,
                              hipStream_t stream) {
    const float* input_seq = (const float*)d_in[0];
    const float* noise     = (const float*)d_in[1];
    const float* J_w       = (const float*)d_in[2];
    const float* b_in      = (const float*)d_in[3];
    const float* c_x       = (const float*)d_in[4];
    const float* wout_w    = (const float*)d_in[5];
    const float* wout_b    = (const float*)d_in[6];

    float* out    = (float*)d_out;       // [B,2]
    float* states = out + 2 * BATCH;     // [T,B,H]

    rnn_scan_kernel<<<BATCH, 64, 0, stream>>>(
        input_seq, noise, J_w, b_in, c_x, states);
    rnn_out_kernel<<<BATCH, 64, 0, stream>>>(states, wout_w, wout_b, out);
}

// Round 3
// 468.062 us; speedup vs baseline: 1.4605x; 1.4605x over previous
//
#include <hip/hip_runtime.h>

// RNN scan: T=750 sequential steps, x[B=1024,H=100].
//   r = tanh(x); x += ALPHA*(-x + r@J^T + u@b_in^T + c_x + 0.1*n)
// R1 structure (1 thread per (b,h), 4 batch/block, r broadcast via LDS,
// 1 barrier/step) + two fixes:
//  - J row pinned in VGPRs via empty asm ("+v") so the allocator cannot
//    rematerialize the (invariant) global loads inside the t-loop.
//  - k-packed v2f FMAs -> v_pk_fma_f32, halving FMA issue count.

typedef float v2f __attribute__((ext_vector_type(2)));

#define TSTEPS 750
#define BATCH  1024
#define HID    100
#define B_PER_BLK 4
#define THREADS (B_PER_BLK * HID)  // 400

constexpr float ALPHA = 0.1f;   // DT/TAU
constexpr float NSTD  = 0.1f;

__device__ __forceinline__ float ftanh(float x) {
    // tanh(x) = 1 - 2/(exp(2x)+1)
    float e = __expf(2.0f * x);
    return 1.0f - 2.0f * __builtin_amdgcn_rcpf(e + 1.0f);
}

__global__ __launch_bounds__(THREADS, 1) void rnn_scan_kernel(
    const float* __restrict__ input_seq,  // [T,B,4]
    const float* __restrict__ noise,      // [T,B,H]
    const float* __restrict__ J_w,        // [H,H]
    const float* __restrict__ b_in,       // [H,4]
    const float* __restrict__ c_x,        // [H]
    float* __restrict__ states)           // [T,B,H]
{
    const int tid = threadIdx.x;
    const int b_local = tid / HID;          // 0..3
    const int h = tid - b_local * HID;      // 0..99
    const int b = blockIdx.x * B_PER_BLK + b_local;

    // J row h as 50 k-pairs: Jk[j] = {J[h,2j], J[h,2j+1]}. 100 VGPRs.
    v2f Jk[50];
    const float4* Jrow = reinterpret_cast<const float4*>(J_w + (size_t)h * HID);
#pragma unroll
    for (int i = 0; i < 25; ++i) {
        float4 a = Jrow[i];
        Jk[2 * i]     = (v2f){a.x, a.y};
        Jk[2 * i + 1] = (v2f){a.z, a.w};
    }
    // Pin: asm-defined values are NOT rematerializable -> must stay live in
    // VGPRs across the whole t-loop (this is the R1/R2 failure mode).
#pragma unroll
    for (int j = 0; j < 50; ++j) asm volatile("" : "+v"(Jk[j]));

    const float4 bin = *reinterpret_cast<const float4*>(b_in + (size_t)h * 4);
    const float cx = c_x[h];

    __shared__ __align__(16) float r_lds[2][B_PER_BLK][HID];

    float x = 0.0f;
    r_lds[0][b_local][h] = 0.0f;  // r(x0) = tanh(0) = 0

    const float* uptr = input_seq + (size_t)b * 4;
    const float* nptr = noise + (size_t)b * HID + h;
    float4 u  = *reinterpret_cast<const float4*>(uptr);   // t=0 (wave-mostly-uniform)
    float  nz = *nptr;

    float* sptr = states + (size_t)b * HID + h;

    __syncthreads();

    for (int t = 0; t < TSTEPS; ++t) {
        // Prefetch t+1 inputs; ~200 cycles of FMA below to hide the latency.
        const int tn = (t + 1 < TSTEPS) ? (t + 1) : t;
        float4 u_next  = *reinterpret_cast<const float4*>(uptr + (size_t)tn * BATCH * 4);
        float  nz_next = nptr[(size_t)tn * BATCH * HID];

        // x_new[h] = sum_k r[k]*J[h,k], k-packed. r reads are wave-uniform per
        // b_local group -> LDS broadcast, conflict-free.
        const float* rb = &r_lds[t & 1][b_local][0];
        v2f a0 = {0.f, 0.f}, a1 = {0.f, 0.f}, a2 = {0.f, 0.f}, a3 = {0.f, 0.f};
#pragma unroll
        for (int i = 0; i < 25; ++i) {
            float4 r4 = *reinterpret_cast<const float4*>(rb + 4 * i);
            v2f r01 = (v2f){r4.x, r4.y};
            v2f r23 = (v2f){r4.z, r4.w};
            if (i & 1) {
                a2 = __builtin_elementwise_fma(Jk[2 * i],     r01, a2);
                a3 = __builtin_elementwise_fma(Jk[2 * i + 1], r23, a3);
            } else {
                a0 = __builtin_elementwise_fma(Jk[2 * i],     r01, a0);
                a1 = __builtin_elementwise_fma(Jk[2 * i + 1], r23, a1);
            }
        }
        v2f av = (a0 + a1) + (a2 + a3);
        float s = av.x + av.y;

        float inp = u.x * bin.x + u.y * bin.y + u.z * bin.z + u.w * bin.w;
        float dx = ALPHA * (-x + s + inp + cx + NSTD * nz);
        x += dx;

        sptr[(size_t)t * BATCH * HID] = x;            // states[t,b,h]
        r_lds[(t + 1) & 1][b_local][h] = ftanh(x);    // next r, alt buffer

        u = u_next; nz = nz_next;
        __syncthreads();  // one barrier per step (double-buffered r_lds)
    }
}

// Readout: out[b,0] = tanh(states[0,b,:]).wout + wb ; out[b,1] = same at T-1.
__global__ __launch_bounds__(64) void rnn_out_kernel(
    const float* __restrict__ states,
    const float* __restrict__ wout_w,
    const float* __restrict__ wout_b,
    float* __restrict__ out)
{
    const int b = blockIdx.x;
    const int l = threadIdx.x;
    const float* s0 = states + (size_t)b * HID;
    const float* sF = states + ((size_t)(TSTEPS - 1) * BATCH + b) * HID;

    float p0 = 0.f, pF = 0.f;
    if (l < HID) {
        p0 = ftanh(s0[l]) * wout_w[l];
        pF = ftanh(sF[l]) * wout_w[l];
    }
    const int l2 = l + 64;
    if (l2 < HID) {
        p0 += ftanh(s0[l2]) * wout_w[l2];
        pF += ftanh(sF[l2]) * wout_w[l2];
    }
#pragma unroll
    for (int off = 32; off > 0; off >>= 1) {
        p0 += __shfl_xor(p0, off, 64);
        pF += __shfl_xor(pF, off, 64);
    }
    if (l == 0) {
        const float wb = wout_b[0];
        out[b * 2 + 0] = p0 + wb;
        out[b * 2 + 1] = pF + wb;
    }
}

extern "C" void kernel_launch(void* const* d_in, const int* in_sizes, int n_in,
                              void* d_out, int out_size, void* d_ws, size_t ws_size,
                              hipStream_t stream) {
    const float* input_seq = (const float*)d_in[0];
    const float* noise     = (const float*)d_in[1];
    const float* J_w       = (const float*)d_in[2];
    const float* b_in      = (const float*)d_in[3];
    const float* c_x       = (const float*)d_in[4];
    const float* wout_w    = (const float*)d_in[5];
    const float* wout_b    = (const float*)d_in[6];

    float* out    = (float*)d_out;       // [B,2]
    float* states = out + 2 * BATCH;     // [T,B,H]

    rnn_scan_kernel<<<BATCH / B_PER_BLK, THREADS, 0, stream>>>(
        input_seq, noise, J_w, b_in, c_x, states);
    rnn_out_kernel<<<BATCH, 64, 0, stream>>>(states, wout_w, wout_b, out);
}